// Round 3
// baseline (481.885 us; speedup 1.0000x reference)
//
#include <hip/hip_runtime.h>
#include <hip/hip_bf16.h>
#include <stdint.h>

typedef unsigned short ushort_t;
using short8   = __attribute__((ext_vector_type(8))) short;
using float4v  = __attribute__((ext_vector_type(4))) float;

__device__ __forceinline__ float bf2f(ushort_t u) {
    union { unsigned int i; float f; } v;
    v.i = ((unsigned int)u) << 16;
    return v.f;
}
__device__ __forceinline__ ushort_t f2b(float f) {
    union { float f; unsigned int i; } v;
    v.f = f;
    unsigned int u = v.i;
    unsigned int r = (u + 0x7fffu + ((u >> 16) & 1u)) >> 16;   // RNE
    return (ushort_t)r;
}

// ---------------------------------------------------------------------------
// Zero fp32 accumulators (ws is poisoned 0xAA before every launch).
// ---------------------------------------------------------------------------
__global__ void zero_k(float4v* __restrict__ p, int n4) {
    int i = blockIdx.x * 256 + threadIdx.x;
    if (i < n4) {
        float4v z = {0.f, 0.f, 0.f, 0.f};
        p[i] = z;
    }
}

// ---------------------------------------------------------------------------
// Convert W1 [128][64] fp32 and W2 [64][128] fp32 to bf16 (once per launch).
// ---------------------------------------------------------------------------
__global__ void convw_k(const float* __restrict__ W1, const float* __restrict__ W2,
                        ushort_t* __restrict__ w1b, ushort_t* __restrict__ w2b) {
    for (int i = threadIdx.x; i < 8192; i += 256) {
        w1b[i] = f2b(W1[i]);
        w2b[i] = f2b(W2[i]);
    }
}

// ---------------------------------------------------------------------------
// Transpose inp [64][N] fp32 -> X [N][64] bf16.
// X is staged in d_out's first half (fp32 out buffer = 2x the bytes of X);
// gather consumes X fully before mlp_k overwrites d_out (stream-ordered).
// ---------------------------------------------------------------------------
__global__ void transpose_k(const float* __restrict__ inp,
                            ushort_t* __restrict__ X, int N) {
    __shared__ float tile[64][65];          // +1 pad: conflict-free both phases
    int tx = threadIdx.x & 63;
    int ty = threadIdx.x >> 6;              // 0..3
    int n0 = blockIdx.x * 64;
#pragma unroll
    for (int r = 0; r < 16; ++r) {
        int d = ty * 16 + r;
        int n = n0 + tx;
        if (n < N) tile[d][tx] = inp[(size_t)d * N + n];
    }
    __syncthreads();
#pragma unroll
    for (int r = 0; r < 16; ++r) {
        int nl = ty * 16 + r;
        int n  = n0 + nl;
        if (n < N) X[(size_t)n * 64 + tx] = f2b(tile[tx][nl]);
    }
}

// ---------------------------------------------------------------------------
// Gather+scatter: one wave per edge; lane = feature dim.
// agg[dst][lane] += X[src][lane]   (fp32 atomics, device scope)
// ---------------------------------------------------------------------------
__global__ void gather_k(const ushort_t* __restrict__ X,
                         const int* __restrict__ src,
                         const int* __restrict__ dst,
                         float* __restrict__ agg, int E) {
    int e    = blockIdx.x * 4 + (threadIdx.x >> 6);
    int lane = threadIdx.x & 63;
    if (e < E) {
        int s = src[e];
        int t = dst[e];
        float v = bf2f(X[(size_t)s * 64 + lane]);
        atomicAdd(agg + (size_t)t * 64 + lane, v);
    }
}

// ---------------------------------------------------------------------------
// Fused 2-layer MLP via bf16 MFMA 16x16x32 (fp32 acc; error << 0.107 thr).
// Block = 256 threads = 4 waves; wave w handles 16 nodes [n0+w*16, +16).
// Frag maps (verified, guide §3):
//   A[m=lane&15][k=(lane>>4)*8+j], B[k=(lane>>4)*8+j][n=lane&15],
//   D[m=(lane>>4)*4+r][n=lane&15]
// ---------------------------------------------------------------------------
#define HPITCH 136   // rows 272B: 16B-aligned, conflict-spread

__global__ __launch_bounds__(256) void mlp_k(
        const float* __restrict__ agg,
        const ushort_t* __restrict__ W1, const float* __restrict__ b1,
        const ushort_t* __restrict__ W2, const float* __restrict__ b2,
        float* __restrict__ out, int N) {
    __shared__ ushort_t h_s[4][16 * HPITCH];

    int wave = threadIdx.x >> 6;
    int lane = threadIdx.x & 63;
    int row  = lane & 15;      // A's m / B's n / D's n
    int quad = lane >> 4;      // 0..3
    int n0   = blockIdx.x * 64 + wave * 16;

    // ---- Layer 1: A fragments from agg (fp32 -> bf16) --------------------
    int anode = n0 + row;
    if (anode > N - 1) anode = N - 1;               // clamp (stores guarded)
    const float* ap = agg + (size_t)anode * 64 + quad * 8;

    short8 a0, a1;
    {
        float4v f0 = *(const float4v*)(ap);
        float4v f1 = *(const float4v*)(ap + 4);
        float4v f2 = *(const float4v*)(ap + 32);
        float4v f3 = *(const float4v*)(ap + 36);
#pragma unroll
        for (int j = 0; j < 4; ++j) {
            a0[j]     = (short)f2b(f0[j]);
            a0[j + 4] = (short)f2b(f1[j]);
            a1[j]     = (short)f2b(f2[j]);
            a1[j + 4] = (short)f2b(f3[j]);
        }
    }

    float4v zero = {0.f, 0.f, 0.f, 0.f};
    float4v acc[8];
#pragma unroll
    for (int nt = 0; nt < 8; ++nt) acc[nt] = zero;

#pragma unroll
    for (int nt = 0; nt < 8; ++nt) {
        const ushort_t* wp = W1 + (size_t)(nt * 16 + row) * 64 + quad * 8;
        short8 bf0 = *(const short8*)(wp);        // k 0..31 slice
        short8 bf1 = *(const short8*)(wp + 32);   // k 32..63 slice
        acc[nt] = __builtin_amdgcn_mfma_f32_16x16x32_bf16(a0, bf0, acc[nt], 0, 0, 0);
        acc[nt] = __builtin_amdgcn_mfma_f32_16x16x32_bf16(a1, bf1, acc[nt], 0, 0, 0);
    }

    // bias + relu -> LDS (bf16), H[m][j] at h_s[wave][m*HPITCH + j]
    ushort_t* hw = h_s[wave];
#pragma unroll
    for (int nt = 0; nt < 8; ++nt) {
        float bias = b1[nt * 16 + row];
#pragma unroll
        for (int r = 0; r < 4; ++r) {
            float v = acc[nt][r] + bias;
            v = v > 0.f ? v : 0.f;
            hw[(quad * 4 + r) * HPITCH + nt * 16 + row] = f2b(v);
        }
    }
    __syncthreads();

    // ---- Layer 2 ---------------------------------------------------------
    short8 a2[4];
#pragma unroll
    for (int kt = 0; kt < 4; ++kt)
        a2[kt] = *(const short8*)(hw + row * HPITCH + kt * 32 + quad * 8);

    float4v acc2[4];
#pragma unroll
    for (int nt = 0; nt < 4; ++nt) acc2[nt] = zero;

#pragma unroll
    for (int nt = 0; nt < 4; ++nt) {
#pragma unroll
        for (int kt = 0; kt < 4; ++kt) {
            short8 bfr = *(const short8*)(W2 + (size_t)(nt * 16 + row) * 128 +
                                          kt * 32 + quad * 8);
            acc2[nt] = __builtin_amdgcn_mfma_f32_16x16x32_bf16(a2[kt], bfr, acc2[nt], 0, 0, 0);
        }
    }

    // ---- Store fp32: out[k_out][node], k_out=nt*16+row, node=n0+quad*4+r -
    int node = n0 + quad * 4;
    if (node < N) {
#pragma unroll
        for (int nt = 0; nt < 4; ++nt) {
            int ko = nt * 16 + row;
            float bias = b2[ko];
            float4v pk;
#pragma unroll
            for (int r = 0; r < 4; ++r) pk[r] = acc2[nt][r] + bias;
            *(float4v*)(out + (size_t)ko * N + node) = pk;
        }
    }
}

// ---------------------------------------------------------------------------
extern "C" void kernel_launch(void* const* d_in, const int* in_sizes, int n_in,
                              void* d_out, int out_size, void* d_ws, size_t ws_size,
                              hipStream_t stream) {
    const float* inp = (const float*)d_in[0];   // [64][N] fp32
    const int*   src = (const int*)d_in[1];
    const int*   dst = (const int*)d_in[2];
    const float* W1  = (const float*)d_in[3];   // [128][64] fp32
    const float* b1  = (const float*)d_in[4];   // [128] fp32
    const float* W2  = (const float*)d_in[5];   // [64][128] fp32
    const float* b2  = (const float*)d_in[6];   // [64] fp32
    float* out = (float*)d_out;                 // [64][N] fp32

    int N = in_sizes[0] / 64;
    int E = in_sizes[1];

    // ws layout: [0, N*64*4) fp32 agg ; then w1b (16KB) ; w2b (16KB)
    float*    agg = (float*)d_ws;
    ushort_t* w1b = (ushort_t*)((char*)d_ws + (size_t)N * 64 * sizeof(float));
    ushort_t* w2b = w1b + 8192;
    // X[N][64] bf16 staged in d_out's first half (12.8 of 25.6 MB); consumed
    // by gather_k before mlp_k overwrites d_out — stream-ordered.
    ushort_t* X = (ushort_t*)d_out;

    int n4 = N * 64 / 4;
    zero_k<<<(n4 + 255) / 256, 256, 0, stream>>>((float4v*)agg, n4);
    convw_k<<<1, 256, 0, stream>>>(W1, W2, w1b, w2b);

    int tb = (N + 63) / 64;
    transpose_k<<<tb, 256, 0, stream>>>(inp, X, N);
    gather_k<<<(E + 3) / 4, 256, 0, stream>>>(X, src, dst, agg, E);
    mlp_k<<<tb, 256, 0, stream>>>(agg, w1b, b1, w2b, b2, out, N);
}

// Round 4
// 411.171 us; speedup vs baseline: 1.1720x; 1.1720x over previous
//
#include <hip/hip_runtime.h>
#include <hip/hip_bf16.h>
#include <stdint.h>

typedef unsigned short ushort_t;
using short8   = __attribute__((ext_vector_type(8))) short;
using float4v  = __attribute__((ext_vector_type(4))) float;
using int4v    = __attribute__((ext_vector_type(4))) int;

__device__ __forceinline__ float bf2f(ushort_t u) {
    union { unsigned int i; float f; } v;
    v.i = ((unsigned int)u) << 16;
    return v.f;
}
__device__ __forceinline__ ushort_t f2b(float f) {
    union { float f; unsigned int i; } v;
    v.f = f;
    unsigned int u = v.i;
    unsigned int r = (u + 0x7fffu + ((u >> 16) & 1u)) >> 16;   // RNE
    return (ushort_t)r;
}

// ---------------------------------------------------------------------------
// Zero int/float region (ws & d_out are poisoned 0xAA before every launch).
// ---------------------------------------------------------------------------
__global__ void zero_k(int4v* __restrict__ p, int n4) {
    int i = blockIdx.x * 256 + threadIdx.x;
    if (i < n4) {
        int4v z = {0, 0, 0, 0};
        p[i] = z;
    }
}

// ---------------------------------------------------------------------------
// Convert W1 [128][64] fp32 and W2 [64][128] fp32 to bf16 (once per launch).
// ---------------------------------------------------------------------------
__global__ void convw_k(const float* __restrict__ W1, const float* __restrict__ W2,
                        ushort_t* __restrict__ w1b, ushort_t* __restrict__ w2b) {
    for (int i = threadIdx.x; i < 8192; i += 256) {
        w1b[i] = f2b(W1[i]);
        w2b[i] = f2b(W2[i]);
    }
}

// ---------------------------------------------------------------------------
// Transpose inp [64][N] fp32 -> X [N][64] bf16 (staged in d_out; consumed by
// agg_k before mlp_k overwrites d_out — stream-ordered, lifetimes disjoint).
// ---------------------------------------------------------------------------
__global__ void transpose_k(const float* __restrict__ inp,
                            ushort_t* __restrict__ X, int N) {
    __shared__ float tile[64][65];
    int tx = threadIdx.x & 63;
    int ty = threadIdx.x >> 6;
    int n0 = blockIdx.x * 64;
#pragma unroll
    for (int r = 0; r < 16; ++r) {
        int d = ty * 16 + r;
        int n = n0 + tx;
        if (n < N) tile[d][tx] = inp[(size_t)d * N + n];
    }
    __syncthreads();
#pragma unroll
    for (int r = 0; r < 16; ++r) {
        int nl = ty * 16 + r;
        int n  = n0 + nl;
        if (n < N) X[(size_t)n * 64 + tx] = f2b(tile[tx][nl]);
    }
}

// ---------------------------------------------------------------------------
// CSR build: histogram of dst
// ---------------------------------------------------------------------------
__global__ void hist_k(const int* __restrict__ dst, int* __restrict__ cnt, int E) {
    int e = blockIdx.x * 256 + threadIdx.x;
    if (e < E) atomicAdd(cnt + dst[e], 1);
}

// ---------------------------------------------------------------------------
// Exclusive scan of cnt[N] -> offs[N]; 1024 elements per 256-thread block.
// ---------------------------------------------------------------------------
__global__ void scan1_k(const int* __restrict__ cnt, int* __restrict__ offs,
                        int* __restrict__ bsum, int N) {
    __shared__ int s[256];
    int t   = threadIdx.x;
    int idx = blockIdx.x * 1024 + t * 4;
    int c0 = 0, c1 = 0, c2 = 0, c3 = 0;
    if (idx + 3 < N) {
        int4v c = *(const int4v*)(cnt + idx);
        c0 = c[0]; c1 = c[1]; c2 = c[2]; c3 = c[3];
    } else {
        if (idx     < N) c0 = cnt[idx];
        if (idx + 1 < N) c1 = cnt[idx + 1];
        if (idx + 2 < N) c2 = cnt[idx + 2];
        if (idx + 3 < N) c3 = cnt[idx + 3];
    }
    int sum = c0 + c1 + c2 + c3;
    s[t] = sum;
    __syncthreads();
#pragma unroll
    for (int off = 1; off < 256; off <<= 1) {
        int v = (t >= off) ? s[t - off] : 0;
        __syncthreads();
        s[t] += v;
        __syncthreads();
    }
    int excl = s[t] - sum;
    int o0 = excl, o1 = o0 + c0, o2 = o1 + c1, o3 = o2 + c2;
    if (idx     < N) offs[idx]     = o0;
    if (idx + 1 < N) offs[idx + 1] = o1;
    if (idx + 2 < N) offs[idx + 2] = o2;
    if (idx + 3 < N) offs[idx + 3] = o3;
    if (t == 0) bsum[blockIdx.x] = s[255];
}

__global__ void scan2_k(int* __restrict__ bsum, int nb) {
    __shared__ int s[128];
    int t = threadIdx.x;                 // 128 threads, nb <= 128
    int v = (t < nb) ? bsum[t] : 0;
    s[t] = v;
    __syncthreads();
#pragma unroll
    for (int off = 1; off < 128; off <<= 1) {
        int u = (t >= off) ? s[t - off] : 0;
        __syncthreads();
        s[t] += u;
        __syncthreads();
    }
    if (t < nb) bsum[t] = s[t] - v;      // exclusive
}

__global__ void scan3_k(int* __restrict__ offs, int* __restrict__ cur,
                        const int* __restrict__ bsum, int N) {
    int add = bsum[blockIdx.x];
    int idx = blockIdx.x * 1024 + threadIdx.x * 4;
#pragma unroll
    for (int j = 0; j < 4; ++j) {
        if (idx + j < N) {
            int v = offs[idx + j] + add;
            offs[idx + j] = v;
            cur[idx + j]  = v;
        }
    }
}

// ---------------------------------------------------------------------------
// Scatter edges into dst-grouped order: esrc[pos] = src[e]
// ---------------------------------------------------------------------------
__global__ void scatter_k(const int* __restrict__ src, const int* __restrict__ dst,
                          int* __restrict__ cur, int* __restrict__ esrc, int E) {
    int e = blockIdx.x * 256 + threadIdx.x;
    if (e < E) {
        int t   = dst[e];
        int pos = atomicAdd(cur + t, 1);
        esrc[pos] = src[e];
    }
}

// ---------------------------------------------------------------------------
// Segmented reduction: one wave per node, lane = feature dim.
// agg[n][lane] = sum over neighbors of X[s][lane]   (no atomics)
// ---------------------------------------------------------------------------
__global__ __launch_bounds__(256) void agg_k(
        const ushort_t* __restrict__ X, const int* __restrict__ esrc,
        const int* __restrict__ offs, const int* __restrict__ cnt,
        float* __restrict__ agg, int N) {
    int n    = blockIdx.x * 4 + (threadIdx.x >> 6);
    int lane = threadIdx.x & 63;
    if (n >= N) return;
    int start = offs[n];
    int d     = cnt[n];
    float a0 = 0.f, a1 = 0.f;
    int i = 0;
    for (; i + 1 < d; i += 2) {
        int s0 = esrc[start + i];
        int s1 = esrc[start + i + 1];
        a0 += bf2f(X[(size_t)s0 * 64 + lane]);
        a1 += bf2f(X[(size_t)s1 * 64 + lane]);
    }
    if (i < d) a0 += bf2f(X[(size_t)esrc[start + i] * 64 + lane]);
    agg[(size_t)n * 64 + lane] = a0 + a1;
}

// ---------------------------------------------------------------------------
// Fused 2-layer MLP via bf16 MFMA 16x16x32 (fp32 acc).
// Frag maps (verified, guide §3):
//   A[m=lane&15][k=(lane>>4)*8+j], B[k=(lane>>4)*8+j][n=lane&15],
//   D[m=(lane>>4)*4+r][n=lane&15]
// ---------------------------------------------------------------------------
#define HPITCH 136

__global__ __launch_bounds__(256) void mlp_k(
        const float* __restrict__ agg,
        const ushort_t* __restrict__ W1, const float* __restrict__ b1,
        const ushort_t* __restrict__ W2, const float* __restrict__ b2,
        float* __restrict__ out, int N) {
    __shared__ ushort_t h_s[4][16 * HPITCH];

    int wave = threadIdx.x >> 6;
    int lane = threadIdx.x & 63;
    int row  = lane & 15;
    int quad = lane >> 4;
    int n0   = blockIdx.x * 64 + wave * 16;

    int anode = n0 + row;
    if (anode > N - 1) anode = N - 1;
    const float* ap = agg + (size_t)anode * 64 + quad * 8;

    short8 a0, a1;
    {
        float4v f0 = *(const float4v*)(ap);
        float4v f1 = *(const float4v*)(ap + 4);
        float4v f2 = *(const float4v*)(ap + 32);
        float4v f3 = *(const float4v*)(ap + 36);
#pragma unroll
        for (int j = 0; j < 4; ++j) {
            a0[j]     = (short)f2b(f0[j]);
            a0[j + 4] = (short)f2b(f1[j]);
            a1[j]     = (short)f2b(f2[j]);
            a1[j + 4] = (short)f2b(f3[j]);
        }
    }

    float4v zero = {0.f, 0.f, 0.f, 0.f};
    float4v acc[8];
#pragma unroll
    for (int nt = 0; nt < 8; ++nt) acc[nt] = zero;

#pragma unroll
    for (int nt = 0; nt < 8; ++nt) {
        const ushort_t* wp = W1 + (size_t)(nt * 16 + row) * 64 + quad * 8;
        short8 bf0 = *(const short8*)(wp);
        short8 bf1 = *(const short8*)(wp + 32);
        acc[nt] = __builtin_amdgcn_mfma_f32_16x16x32_bf16(a0, bf0, acc[nt], 0, 0, 0);
        acc[nt] = __builtin_amdgcn_mfma_f32_16x16x32_bf16(a1, bf1, acc[nt], 0, 0, 0);
    }

    ushort_t* hw = h_s[wave];
#pragma unroll
    for (int nt = 0; nt < 8; ++nt) {
        float bias = b1[nt * 16 + row];
#pragma unroll
        for (int r = 0; r < 4; ++r) {
            float v = acc[nt][r] + bias;
            v = v > 0.f ? v : 0.f;
            hw[(quad * 4 + r) * HPITCH + nt * 16 + row] = f2b(v);
        }
    }
    __syncthreads();

    short8 a2[4];
#pragma unroll
    for (int kt = 0; kt < 4; ++kt)
        a2[kt] = *(const short8*)(hw + row * HPITCH + kt * 32 + quad * 8);

    float4v acc2[4];
#pragma unroll
    for (int nt = 0; nt < 4; ++nt) acc2[nt] = zero;

#pragma unroll
    for (int nt = 0; nt < 4; ++nt) {
#pragma unroll
        for (int kt = 0; kt < 4; ++kt) {
            short8 bfr = *(const short8*)(W2 + (size_t)(nt * 16 + row) * 128 +
                                          kt * 32 + quad * 8);
            acc2[nt] = __builtin_amdgcn_mfma_f32_16x16x32_bf16(a2[kt], bfr, acc2[nt], 0, 0, 0);
        }
    }

    int node = n0 + quad * 4;
    if (node < N) {
#pragma unroll
        for (int nt = 0; nt < 4; ++nt) {
            int ko = nt * 16 + row;
            float bias = b2[ko];
            float4v pk;
#pragma unroll
            for (int r = 0; r < 4; ++r) pk[r] = acc2[nt][r] + bias;
            *(float4v*)(out + (size_t)ko * N + node) = pk;
        }
    }
}

// ---------------------------------------------------------------------------
extern "C" void kernel_launch(void* const* d_in, const int* in_sizes, int n_in,
                              void* d_out, int out_size, void* d_ws, size_t ws_size,
                              hipStream_t stream) {
    const float* inp = (const float*)d_in[0];   // [64][N] fp32
    const int*   src = (const int*)d_in[1];
    const int*   dst = (const int*)d_in[2];
    const float* W1  = (const float*)d_in[3];   // [128][64] fp32
    const float* b1  = (const float*)d_in[4];   // [128] fp32
    const float* W2  = (const float*)d_in[5];   // [64][128] fp32
    const float* b2  = (const float*)d_in[6];   // [64] fp32
    float* out = (float*)d_out;                 // [64][N] fp32

    int N = in_sizes[0] / 64;
    int E = in_sizes[1];

    // ws: agg fp32[N*64] (25.6 MB) + w1b/w2b bf16 (32 KB) + bsum int[128]
    float*    agg = (float*)d_ws;
    ushort_t* w1b = (ushort_t*)((char*)d_ws + (size_t)N * 64 * sizeof(float));
    ushort_t* w2b = w1b + 8192;
    int*      bsum = (int*)(w2b + 8192);

    // d_out staging (all dead before mlp_k overwrites d_out):
    //   X bf16[N*64] (12.8 MB) | esrc int[E] (6.4 MB) | cnt,offs,cur int[N] each
    char* ob = (char*)d_out;
    ushort_t* X    = (ushort_t*)ob;
    int*      esrc = (int*)(ob + (size_t)N * 64 * 2);
    int*      cnt  = (int*)(ob + (size_t)N * 64 * 2 + (size_t)E * 4);
    int*      offs = cnt + N;
    int*      cur  = offs + N;

    int nb1 = (N + 1023) / 1024;        // scan blocks (<=128 for N<=131072)

    convw_k<<<1, 256, 0, stream>>>(W1, W2, w1b, w2b);
    zero_k<<<(N / 4 + 255) / 256, 256, 0, stream>>>((int4v*)cnt, N / 4);

    int tb = (N + 63) / 64;
    transpose_k<<<tb, 256, 0, stream>>>(inp, X, N);

    hist_k<<<(E + 255) / 256, 256, 0, stream>>>(dst, cnt, E);
    scan1_k<<<nb1, 256, 0, stream>>>(cnt, offs, bsum, N);
    scan2_k<<<1, 128, 0, stream>>>(bsum, nb1);
    scan3_k<<<nb1, 256, 0, stream>>>(offs, cur, bsum, N);
    scatter_k<<<(E + 255) / 256, 256, 0, stream>>>(src, dst, cur, esrc, E);
    agg_k<<<(N + 3) / 4, 256, 0, stream>>>(X, esrc, offs, cnt, agg, N);

    mlp_k<<<tb, 256, 0, stream>>>(agg, w1b, b1, w2b, b2, out, N);
}